// Round 1
// baseline (552.927 us; speedup 1.0000x reference)
//
#include <hip/hip_runtime.h>
#include <cstdint>

#define LSTM_B 256
#define LSTM_T 512
#define LSTM_D 128
#define LSTM_U 128

typedef _Float16 h2_t __attribute__((ext_vector_type(2)));

static __device__ __forceinline__ h2_t as_h2(uint32_t u) {
  return __builtin_bit_cast(h2_t, u);
}
static __device__ __forceinline__ uint32_t as_u32(h2_t h) {
  return __builtin_bit_cast(uint32_t, h);
}
static __device__ __forceinline__ uint32_t pack2(float a, float b) {
  h2_t h;
  h.x = (_Float16)a;
  h.y = (_Float16)b;
  return as_u32(h);
}
static __device__ __forceinline__ float dot2acc(uint32_t a, uint32_t w, float acc) {
#if __has_builtin(__builtin_amdgcn_fdot2)
  return __builtin_amdgcn_fdot2(as_h2(a), as_h2(w), acc, false);
#else
  h2_t ha = as_h2(a), hw = as_h2(w);
  return acc + (float)ha.x * (float)hw.x + (float)ha.y * (float)hw.y;
#endif
}
static __device__ __forceinline__ float sigm(float v) {
  return 1.0f / (1.0f + __expf(-v));
}
static __device__ __forceinline__ float tanh_(float v) {
  // robust for large |v|: exp -> inf gives correct +/-1 limits
  return 1.0f - 2.0f / (__expf(2.0f * v) + 1.0f);
}

// One workgroup per batch element. Thread t owns gate column t (of 4*U=512).
// Its weight column W[0:256, t] is register-resident as 128 packed-f16 dwords.
// Activation vector a = [x_t (128) ; h (128)] lives in LDS as f16, double-buffered.
__global__ __launch_bounds__(512, 2) void lstm_fused_kernel(
    const float* __restrict__ x,     // [B, T, D]
    const float* __restrict__ W,     // [D+U, 4U] = [256, 512], gate order i,j,f,o
    const float* __restrict__ bias,  // [4U]
    float* __restrict__ out)         // [B, T, U]
{
  __shared__ __align__(16) uint32_t a_lds[2][128];  // 2 buffers x 256 halves
  __shared__ float g_lds[512];

  const int tid = threadIdx.x;
  const int b = blockIdx.x;

  // ---- load & pack this thread's weight column into registers ----
  uint32_t wreg[128];
#pragma unroll
  for (int q4 = 0; q4 < 32; ++q4) {
    float f[8];
#pragma unroll
    for (int r = 0; r < 8; ++r) f[r] = W[(q4 * 8 + r) * 512 + tid];
#pragma unroll
    for (int rr = 0; rr < 4; ++rr)
      wreg[q4 * 4 + rr] = pack2(f[2 * rr], f[2 * rr + 1]);
  }
  const float bj = bias[tid];

  const float* __restrict__ xb = x + (size_t)b * (LSTM_T * LSTM_D);
  float* __restrict__ ob = out + (size_t)b * (LSTM_T * LSTM_U);

  // ---- init buffer 0: x_0 (f16) and h = 0 ----
  if (tid < 32) {
    float4 x4 = reinterpret_cast<const float4*>(xb)[tid];
    reinterpret_cast<uint2*>(&a_lds[0][0])[tid] =
        make_uint2(pack2(x4.x, x4.y), pack2(x4.z, x4.w));
  }
  if (tid >= 64 && tid < 128) a_lds[0][tid] = 0u;  // h region: dwords 64..127
  __syncthreads();

  float c = 0.0f;  // cell state, valid for tid < 128
  int p = 0;

  for (int t = 0; t < LSTM_T; ++t) {
    // prefetch x_{t+1} into registers (latency hidden under the dot)
    float4 xp;
    const bool pf = (tid < 32) && (t + 1 < LSTM_T);
    if (pf) xp = reinterpret_cast<const float4*>(xb + (t + 1) * LSTM_D)[tid];

    // ---- gate pre-activation: dot over 256 f16 values, 4 independent accs ----
    const uint4* av = reinterpret_cast<const uint4*>(&a_lds[p][0]);
    float a0 = bj, a1 = 0.0f, a2 = 0.0f, a3 = 0.0f;
#pragma unroll
    for (int q = 0; q < 32; ++q) {
      uint4 a4 = av[q];  // broadcast ds_read_b128 (same addr all lanes)
      a0 = dot2acc(a4.x, wreg[4 * q + 0], a0);
      a1 = dot2acc(a4.y, wreg[4 * q + 1], a1);
      a2 = dot2acc(a4.z, wreg[4 * q + 2], a2);
      a3 = dot2acc(a4.w, wreg[4 * q + 3], a3);
    }
    g_lds[tid] = (a0 + a1) + (a2 + a3);
    __syncthreads();

    // ---- epilogue: LSTM cell update on threads 0..127 ----
    if (tid < 128) {
      const float gi = g_lds[tid];
      const float gj = g_lds[128 + tid];
      const float gf = g_lds[256 + tid];
      const float go = g_lds[384 + tid];
      c = c * sigm(gf + 1.0f) + sigm(gi) * tanh_(gj);
      const float h = tanh_(c) * sigm(go);
      ob[t * LSTM_U + tid] = h;
      reinterpret_cast<_Float16*>(&a_lds[p ^ 1][64])[tid] = (_Float16)h;
    }
    // stage x_{t+1} (f16) into the next buffer
    if (pf) {
      reinterpret_cast<uint2*>(&a_lds[p ^ 1][0])[tid] =
          make_uint2(pack2(xp.x, xp.y), pack2(xp.z, xp.w));
    }
    __syncthreads();
    p ^= 1;
  }
}

extern "C" void kernel_launch(void* const* d_in, const int* in_sizes, int n_in,
                              void* d_out, int out_size, void* d_ws, size_t ws_size,
                              hipStream_t stream) {
  (void)in_sizes; (void)n_in; (void)d_ws; (void)ws_size; (void)out_size;
  const float* x = (const float*)d_in[0];
  const float* W = (const float*)d_in[1];
  const float* b = (const float*)d_in[2];
  float* out = (float*)d_out;
  lstm_fused_kernel<<<LSTM_B, 512, 0, stream>>>(x, W, b, out);
}